// Round 1
// baseline (167.315 us; speedup 1.0000x reference)
//
#include <hip/hip_runtime.h>
#include <cmath>

// SSIM fused kernel for B=16, C=3, H=W=512 fp32 images.
// Separable 11-tap Gaussian conv: horizontal via LDS row (double-buffered),
// vertical via per-thread register ring buffer (static indices via unroll-11).
// One block = one (plane, 32-row stripe); 512 threads = 1 column each.

#define IMG_H 512
#define IMG_W 512
#define STRIPE 32
#define NSTR (IMG_H / STRIPE)      // 16
#define NPLANES 48                 // 16*3
#define NBLOCKS (NPLANES * NSTR)   // 768
#define SSIM_C1 (0.01f * 0.01f)
#define SSIM_C2 (0.03f * 0.03f)

struct W11 { float w[11]; };

__launch_bounds__(512, 4)
__global__ void ssim_main(const float* __restrict__ img1,
                          const float* __restrict__ img2,
                          float* __restrict__ blockSums, W11 wv) {
    // [buf][img][col]; cols 0..521 used (5 halo each side), pad stride 544
    __shared__ float tb[2][2][544];
    __shared__ float red[8];

    const int x = threadIdx.x;            // 0..511, one output column
    const int bid = blockIdx.x;
    const int plane = bid >> 4;           // /NSTR
    const int stripe = bid & (NSTR - 1);
    const int y0 = stripe * STRIPE;
    const size_t base = (size_t)plane * (IMG_H * IMG_W);

    // zero the halo pads once (cols 0..4 and 517..521, both bufs, both imgs)
    if (x < 10) {
        const int col = (x < 5) ? x : (x + 512);
        tb[0][0][col] = 0.f; tb[0][1][col] = 0.f;
        tb[1][0][col] = 0.f; tb[1][1][col] = 0.f;
    }

    float ring[5][11];   // vertical ring buffer, static-indexed
    float acc = 0.f;

    // prefetch row for i=0 (r = y0-5)
    float pa = 0.f, pb = 0.f;
    {
        const int r0 = y0 - 5;
        if (r0 >= 0) {   // r0 < IMG_H always here
            pa = img1[base + (size_t)r0 * IMG_W + x];
            pb = img2[base + (size_t)r0 * IMG_W + x];
        }
    }

    int buf = 0;
#pragma unroll 1
    for (int c = 0; c < 4; ++c) {
#pragma unroll
        for (int j = 0; j < 11; ++j) {
            const int i = c * 11 + j;      // 0..43; only 0..41 do work
            if (i < 42) {                  // block-uniform guard
                // stage current row into LDS
                tb[buf][0][x + 5] = pa;
                tb[buf][1][x + 5] = pb;
                // prefetch next row (hidden behind barrier + compute)
                pa = 0.f; pb = 0.f;
                const int rn = y0 - 4 + i;
                if (i + 1 < 42 && rn >= 0 && rn < IMG_H) {
                    pa = img1[base + (size_t)rn * IMG_W + x];
                    pb = img2[base + (size_t)rn * IMG_W + x];
                }
                __syncthreads();
                // horizontal 11-tap conv of the 5 quantities, on the fly
                float h0 = 0.f, h1 = 0.f, h2 = 0.f, h3 = 0.f, h4 = 0.f;
#pragma unroll
                for (int k = 0; k < 11; ++k) {
                    const float ta = tb[buf][0][x + k];
                    const float tbv = tb[buf][1][x + k];
                    const float w = wv.w[k];
                    const float wa = w * ta, wb = w * tbv;
                    h0 = fmaf(w, ta, h0);    // conv(img1)
                    h1 = fmaf(w, tbv, h1);   // conv(img2)
                    h2 = fmaf(wa, ta, h2);   // conv(img1*img1)
                    h3 = fmaf(wb, tbv, h3);  // conv(img2*img2)
                    h4 = fmaf(wa, tbv, h4);  // conv(img1*img2)
                }
                ring[0][j] = h0; ring[1][j] = h1; ring[2][j] = h2;
                ring[3][j] = h3; ring[4][j] = h4;

                if (i >= 10) {  // uniform; output row y = y0 + i - 10
                    float v0 = 0.f, v1 = 0.f, v2 = 0.f, v3 = 0.f, v4 = 0.f;
#pragma unroll
                    for (int k = 0; k < 11; ++k) {
                        const int s = (j + 1 + k) % 11;  // static per (j,k)
                        const float w = wv.w[k];
                        v0 = fmaf(w, ring[0][s], v0);
                        v1 = fmaf(w, ring[1][s], v1);
                        v2 = fmaf(w, ring[2][s], v2);
                        v3 = fmaf(w, ring[3][s], v3);
                        v4 = fmaf(w, ring[4][s], v4);
                    }
                    const float mu11 = v0 * v0;
                    const float mu22 = v1 * v1;
                    const float mu12 = v0 * v1;
                    const float num = (2.f * mu12 + SSIM_C1) *
                                      (2.f * (v4 - mu12) + SSIM_C2);
                    const float den = (mu11 + mu22 + SSIM_C1) *
                                      ((v2 - mu11) + (v3 - mu22) + SSIM_C2);
                    acc += num / den;
                }
                buf ^= 1;
            }
        }
    }

    // block reduction: wave shuffle, then 8 wave-sums via LDS
#pragma unroll
    for (int off = 32; off >= 1; off >>= 1)
        acc += __shfl_down(acc, off, 64);
    const int wave = x >> 6, lane = x & 63;
    if (lane == 0) red[wave] = acc;
    __syncthreads();
    if (x == 0) {
        float s = 0.f;
#pragma unroll
        for (int k = 0; k < 8; ++k) s += red[k];
        blockSums[bid] = s;
    }
}

__global__ void ssim_reduce(const float* __restrict__ bs,
                            float* __restrict__ out) {
    __shared__ double red[4];
    const int t = threadIdx.x;  // 256 threads
    double a = 0.0;
    for (int idx = t; idx < NBLOCKS; idx += 256) a += (double)bs[idx];
#pragma unroll
    for (int off = 32; off >= 1; off >>= 1)
        a += __shfl_down(a, off, 64);
    const int wave = t >> 6, lane = t & 63;
    if (lane == 0) red[wave] = a;
    __syncthreads();
    if (t == 0) {
        const double s = red[0] + red[1] + red[2] + red[3];
        out[0] = (float)(s / (double)((double)NPLANES * IMG_H * IMG_W));
    }
}

extern "C" void kernel_launch(void* const* d_in, const int* in_sizes, int n_in,
                              void* d_out, int out_size, void* d_ws, size_t ws_size,
                              hipStream_t stream) {
    const float* img1 = (const float*)d_in[0];
    const float* img2 = (const float*)d_in[1];
    float* out = (float*)d_out;
    float* bs = (float*)d_ws;   // 768 floats of scratch

    // Gaussian weights, faithful to reference: center 5.5, sigma 1.5,
    // computed in double then normalized and cast to fp32.
    W11 wv;
    double g[11], s = 0.0;
    for (int i = 0; i < 11; ++i) {
        const double d = (double)i - 5.5;
        g[i] = exp(-(d * d) / (2.0 * 1.5 * 1.5));
        s += g[i];
    }
    for (int i = 0; i < 11; ++i) wv.w[i] = (float)(g[i] / s);

    ssim_main<<<NBLOCKS, 512, 0, stream>>>(img1, img2, bs, wv);
    ssim_reduce<<<1, 256, 0, stream>>>(bs, out);
}

// Round 2
// 153.616 us; speedup vs baseline: 1.0892x; 1.0892x over previous
//
#include <hip/hip_runtime.h>
#include <cmath>

// SSIM fused kernel for B=16, C=3, H=W=512 fp32 images.
// Separable 11-tap Gaussian. Horizontal conv via float2-interleaved LDS rows
// (double-buffered, ds_read_b64); vertical via per-thread register ring of
// FOUR quantities: conv(a), conv(b), conv(a^2+b^2), conv(ab) — SSIM only
// needs sigma1^2+sigma2^2, so the two square convs collapse into one.
// One block = one (plane, 32-row stripe); 512 threads = 1 column each.

#define IMG_H 512
#define IMG_W 512
#define STRIPE 32
#define NSTR (IMG_H / STRIPE)      // 16
#define NPLANES 48                 // 16*3
#define NBLOCKS (NPLANES * NSTR)   // 768
#define SSIM_C1 (0.01f * 0.01f)
#define SSIM_C2 (0.03f * 0.03f)

struct W11 { float w[11]; };

__launch_bounds__(512, 4)
__global__ void ssim_main(const float* __restrict__ img1,
                          const float* __restrict__ img2,
                          float* __restrict__ blockSums, W11 wv) {
    // interleaved (a,b) pairs; cols 0..521 used (5 halo each side), pad 528
    __shared__ float2 tb[2][528];
    __shared__ float red[8];

    const int x = threadIdx.x;            // 0..511, one output column
    const int bid = blockIdx.x;
    const int plane = bid >> 4;           // /NSTR
    const int stripe = bid & (NSTR - 1);
    const int y0 = stripe * STRIPE;
    const size_t base = (size_t)plane * (IMG_H * IMG_W);

    // zero halo pads (cols 0..4 and 517..521, both buffers)
    if (x < 10) {
        const int col = (x < 5) ? x : (x + 512);
        tb[0][col] = make_float2(0.f, 0.f);
        tb[1][col] = make_float2(0.f, 0.f);
    }

    // vertical ring buffers, static-indexed via unroll
    float rA[11], rB[11], rS[11], rP[11];
    float acc = 0.f;

    // prefetch first row (r = y0-5)
    float pa = 0.f, pb = 0.f;
    {
        const int r0 = y0 - 5;
        if (r0 >= 0) {
            pa = img1[base + (size_t)r0 * IMG_W + x];
            pb = img2[base + (size_t)r0 * IMG_W + x];
        }
    }

    int buf = 0;
#pragma unroll 1
    for (int c = 0; c < 4; ++c) {
#pragma unroll
        for (int j = 0; j < 11; ++j) {
            const int i = c * 11 + j;      // 0..43; only 0..41 do work
            if (i < 42) {                  // block-uniform guard
                // stage current row into LDS as interleaved pair
                tb[buf][x + 5] = make_float2(pa, pb);
                // prefetch next row (hidden behind barrier + compute)
                pa = 0.f; pb = 0.f;
                const int rn = y0 - 4 + i;
                if (i + 1 < 42 && rn >= 0 && rn < IMG_H) {
                    pa = img1[base + (size_t)rn * IMG_W + x];
                    pb = img2[base + (size_t)rn * IMG_W + x];
                }
                __syncthreads();
                // horizontal 11-tap conv of the 4 quantities
                float h0 = 0.f, h1 = 0.f, h2 = 0.f, h3 = 0.f;
#pragma unroll
                for (int k = 0; k < 11; ++k) {
                    const float2 t = tb[buf][x + k];   // ds_read_b64
                    const float w = wv.w[k];           // SGPR
                    const float sq = fmaf(t.y, t.y, t.x * t.x); // a^2+b^2
                    const float pr = t.x * t.y;                  // a*b
                    h0 = fmaf(w, t.x, h0);
                    h1 = fmaf(w, t.y, h1);
                    h2 = fmaf(w, sq, h2);
                    h3 = fmaf(w, pr, h3);
                }
                rA[j] = h0; rB[j] = h1; rS[j] = h2; rP[j] = h3;

                if (i >= 10) {  // uniform; output row y = y0 + i - 10
                    float vA = 0.f, vB = 0.f, vS = 0.f, vP = 0.f;
#pragma unroll
                    for (int k = 0; k < 11; ++k) {
                        const int s = (j + 1 + k) % 11;  // static per (j,k)
                        const float w = wv.w[k];
                        vA = fmaf(w, rA[s], vA);
                        vB = fmaf(w, rB[s], vB);
                        vS = fmaf(w, rS[s], vS);
                        vP = fmaf(w, rP[s], vP);
                    }
                    const float mu11 = vA * vA;
                    const float mu22 = vB * vB;
                    const float mu12 = vA * vB;
                    const float num = fmaf(2.f, mu12, SSIM_C1) *
                                      fmaf(2.f, vP - mu12, SSIM_C2);
                    const float d1  = mu11 + mu22;
                    const float den = (d1 + SSIM_C1) * ((vS - d1) + SSIM_C2);
                    acc = fmaf(num, __builtin_amdgcn_rcpf(den), acc);
                }
                buf ^= 1;
            }
        }
    }

    // block reduction: wave shuffle, then 8 wave-sums via LDS
#pragma unroll
    for (int off = 32; off >= 1; off >>= 1)
        acc += __shfl_down(acc, off, 64);
    const int wave = x >> 6, lane = x & 63;
    if (lane == 0) red[wave] = acc;
    __syncthreads();
    if (x == 0) {
        float s = 0.f;
#pragma unroll
        for (int k = 0; k < 8; ++k) s += red[k];
        blockSums[bid] = s;
    }
}

__global__ void ssim_reduce(const float* __restrict__ bs,
                            float* __restrict__ out) {
    __shared__ double red[4];
    const int t = threadIdx.x;  // 256 threads
    double a = 0.0;
    for (int idx = t; idx < NBLOCKS; idx += 256) a += (double)bs[idx];
#pragma unroll
    for (int off = 32; off >= 1; off >>= 1)
        a += __shfl_down(a, off, 64);
    const int wave = t >> 6, lane = t & 63;
    if (lane == 0) red[wave] = a;
    __syncthreads();
    if (t == 0) {
        const double s = red[0] + red[1] + red[2] + red[3];
        out[0] = (float)(s / (double)((double)NPLANES * IMG_H * IMG_W));
    }
}

extern "C" void kernel_launch(void* const* d_in, const int* in_sizes, int n_in,
                              void* d_out, int out_size, void* d_ws, size_t ws_size,
                              hipStream_t stream) {
    const float* img1 = (const float*)d_in[0];
    const float* img2 = (const float*)d_in[1];
    float* out = (float*)d_out;
    float* bs = (float*)d_ws;   // 768 floats of scratch

    // Gaussian weights, faithful to reference: center 5.5, sigma 1.5
    W11 wv;
    double g[11], s = 0.0;
    for (int i = 0; i < 11; ++i) {
        const double d = (double)i - 5.5;
        g[i] = exp(-(d * d) / (2.0 * 1.5 * 1.5));
        s += g[i];
    }
    for (int i = 0; i < 11; ++i) wv.w[i] = (float)(g[i] / s);

    ssim_main<<<NBLOCKS, 512, 0, stream>>>(img1, img2, bs, wv);
    ssim_reduce<<<1, 256, 0, stream>>>(bs, out);
}

// Round 3
// 150.277 us; speedup vs baseline: 1.1134x; 1.0222x over previous
//
#include <hip/hip_runtime.h>
#include <cmath>

// SSIM fused kernel for B=16, C=3, H=W=512 fp32 images.
// Separable 11-tap Gaussian. Horizontal conv via float2-interleaved LDS rows
// (double-buffered, ds_read_b64); vertical via per-thread register ring of
// FOUR quantities: conv(a), conv(b), conv(a^2+b^2), conv(ab).
// One block = one (plane, 32-row stripe); 512 threads = 1 column each.
//
// launch_bounds(512,2): 2 waves/EU -> 128 VGPR cap. At (512,4) the 64-VGPR
// cap forced the 44-float ring into AGPRs -> v_accvgpr_read/write churn
// (~88 extra VALU instrs/row). R2 rocprof: VGPR_Count=44, ~2x instr bloat.

#define IMG_H 512
#define IMG_W 512
#define STRIPE 32
#define NSTR (IMG_H / STRIPE)      // 16
#define NPLANES 48                 // 16*3
#define NBLOCKS (NPLANES * NSTR)   // 768
#define SSIM_C1 (0.01f * 0.01f)
#define SSIM_C2 (0.03f * 0.03f)

struct W11 { float w[11]; };

__launch_bounds__(512, 2)
__global__ void ssim_main(const float* __restrict__ img1,
                          const float* __restrict__ img2,
                          float* __restrict__ blockSums, W11 wv) {
    // interleaved (a,b) pairs; cols 0..521 used (5 halo each side), pad 528
    __shared__ float2 tb[2][528];
    __shared__ float red[8];

    const int x = threadIdx.x;            // 0..511, one output column
    const int bid = blockIdx.x;
    const int plane = bid >> 4;           // /NSTR
    const int stripe = bid & (NSTR - 1);
    const int y0 = stripe * STRIPE;
    const size_t base = (size_t)plane * (IMG_H * IMG_W);

    // zero halo pads (cols 0..4 and 517..521, both buffers)
    if (x < 10) {
        const int col = (x < 5) ? x : (x + 512);
        tb[0][col] = make_float2(0.f, 0.f);
        tb[1][col] = make_float2(0.f, 0.f);
    }

    // vertical ring buffers, static-indexed via unroll
    float rA[11], rB[11], rS[11], rP[11];
    float acc = 0.f;

    // prefetch first row (r = y0-5)
    float pa = 0.f, pb = 0.f;
    {
        const int r0 = y0 - 5;
        if (r0 >= 0) {
            pa = img1[base + (size_t)r0 * IMG_W + x];
            pb = img2[base + (size_t)r0 * IMG_W + x];
        }
    }

    int buf = 0;
#pragma unroll 1
    for (int c = 0; c < 4; ++c) {
#pragma unroll
        for (int j = 0; j < 11; ++j) {
            const int i = c * 11 + j;      // 0..43; only 0..41 do work
            if (i < 42) {                  // block-uniform guard
                // stage current row into LDS as interleaved pair
                tb[buf][x + 5] = make_float2(pa, pb);
                // prefetch next row (hidden behind barrier + compute)
                pa = 0.f; pb = 0.f;
                const int rn = y0 - 4 + i;
                if (i + 1 < 42 && rn >= 0 && rn < IMG_H) {
                    pa = img1[base + (size_t)rn * IMG_W + x];
                    pb = img2[base + (size_t)rn * IMG_W + x];
                }
                __syncthreads();
                // horizontal 11-tap conv of the 4 quantities
                float h0 = 0.f, h1 = 0.f, h2 = 0.f, h3 = 0.f;
#pragma unroll
                for (int k = 0; k < 11; ++k) {
                    const float2 t = tb[buf][x + k];   // ds_read_b64
                    const float w = wv.w[k];           // SGPR
                    const float sq = fmaf(t.y, t.y, t.x * t.x); // a^2+b^2
                    const float pr = t.x * t.y;                  // a*b
                    h0 = fmaf(w, t.x, h0);
                    h1 = fmaf(w, t.y, h1);
                    h2 = fmaf(w, sq, h2);
                    h3 = fmaf(w, pr, h3);
                }
                rA[j] = h0; rB[j] = h1; rS[j] = h2; rP[j] = h3;

                if (i >= 10) {  // uniform; output row y = y0 + i - 10
                    float vA = 0.f, vB = 0.f, vS = 0.f, vP = 0.f;
#pragma unroll
                    for (int k = 0; k < 11; ++k) {
                        const int s = (j + 1 + k) % 11;  // static per (j,k)
                        const float w = wv.w[k];
                        vA = fmaf(w, rA[s], vA);
                        vB = fmaf(w, rB[s], vB);
                        vS = fmaf(w, rS[s], vS);
                        vP = fmaf(w, rP[s], vP);
                    }
                    const float mu11 = vA * vA;
                    const float mu22 = vB * vB;
                    const float mu12 = vA * vB;
                    const float num = fmaf(2.f, mu12, SSIM_C1) *
                                      fmaf(2.f, vP - mu12, SSIM_C2);
                    const float d1  = mu11 + mu22;
                    const float den = (d1 + SSIM_C1) * ((vS - d1) + SSIM_C2);
                    acc = fmaf(num, __builtin_amdgcn_rcpf(den), acc);
                }
                buf ^= 1;
            }
        }
    }

    // block reduction: wave shuffle, then 8 wave-sums via LDS
#pragma unroll
    for (int off = 32; off >= 1; off >>= 1)
        acc += __shfl_down(acc, off, 64);
    const int wave = x >> 6, lane = x & 63;
    if (lane == 0) red[wave] = acc;
    __syncthreads();
    if (x == 0) {
        float s = 0.f;
#pragma unroll
        for (int k = 0; k < 8; ++k) s += red[k];
        blockSums[bid] = s;
    }
}

__global__ void ssim_reduce(const float* __restrict__ bs,
                            float* __restrict__ out) {
    __shared__ double red[4];
    const int t = threadIdx.x;  // 256 threads
    double a = 0.0;
    for (int idx = t; idx < NBLOCKS; idx += 256) a += (double)bs[idx];
#pragma unroll
    for (int off = 32; off >= 1; off >>= 1)
        a += __shfl_down(a, off, 64);
    const int wave = t >> 6, lane = t & 63;
    if (lane == 0) red[wave] = a;
    __syncthreads();
    if (t == 0) {
        const double s = red[0] + red[1] + red[2] + red[3];
        out[0] = (float)(s / (double)((double)NPLANES * IMG_H * IMG_W));
    }
}

extern "C" void kernel_launch(void* const* d_in, const int* in_sizes, int n_in,
                              void* d_out, int out_size, void* d_ws, size_t ws_size,
                              hipStream_t stream) {
    const float* img1 = (const float*)d_in[0];
    const float* img2 = (const float*)d_in[1];
    float* out = (float*)d_out;
    float* bs = (float*)d_ws;   // 768 floats of scratch

    // Gaussian weights, faithful to reference: center 5.5, sigma 1.5
    W11 wv;
    double g[11], s = 0.0;
    for (int i = 0; i < 11; ++i) {
        const double d = (double)i - 5.5;
        g[i] = exp(-(d * d) / (2.0 * 1.5 * 1.5));
        s += g[i];
    }
    for (int i = 0; i < 11; ++i) wv.w[i] = (float)(g[i] / s);

    ssim_main<<<NBLOCKS, 512, 0, stream>>>(img1, img2, bs, wv);
    ssim_reduce<<<1, 256, 0, stream>>>(bs, out);
}